// Round 15
// baseline (158.820 us; speedup 1.0000x reference)
//
#include <hip/hip_runtime.h>
#include <hip/hip_fp16.h>

#define IN_DIM 128
#define HID 64
#define NEG 0.01f
#define NBUCK 512     // padded bucket count (real B = ceil(M/256) = 391)
#define EPT 8         // edges per thread per partition round (round = 2048 edges)

typedef unsigned int uint;
typedef unsigned short u16;
typedef __attribute__((ext_vector_type(8))) _Float16 h8v;  // 8 f16 (4 VGPR) MFMA frag
typedef __attribute__((ext_vector_type(4))) float f4v;     // MFMA acc

__device__ __forceinline__ u16 f16r(float x) {
    __half h = __float2half_rn(x);
    return *reinterpret_cast<u16*>(&h);
}
__device__ __forceinline__ uint h2pack(float a, float b) {
    __half2 h = __float22half2_rn(make_float2(a, b));
    return *reinterpret_cast<uint*>(&h);
}
__device__ __forceinline__ __half2 u2h(uint u) { return *reinterpret_cast<__half2*>(&u); }
__device__ __forceinline__ h8v pack8h(float4 x, float4 y) {
    uint4 qq = make_uint4(h2pack(x.x, x.y), h2pack(x.z, x.w),
                          h2pack(y.x, y.y), h2pack(y.z, y.w));
    return *reinterpret_cast<h8v*>(&qq);
}

// ---------- weight fragment prep (+ gcnt/done zeroing) ----------
__global__ __launch_bounds__(256) void prep_frags(const float* __restrict__ W1a,
                                                  const float* __restrict__ W1b,
                                                  const float* __restrict__ W2a,
                                                  const float* __restrict__ W2b,
                                                  u16* __restrict__ wf,
                                                  int* __restrict__ gcnt,
                                                  int* __restrict__ done) {
    int t = threadIdx.x;
    for (int i = t; i < NBUCK; i += 256) gcnt[i] = 0;
    if (t == 0) *done = 0;
    for (int task = t; task < 40 * 64; task += 256) {
        int f = task >> 6, l = task & 63;
        const float* W;
        int kt, nt;
        if (f < 16)      { W = W1a; kt = f & 3;        nt = f >> 2; }
        else if (f < 24) { W = W1b; kt = (f - 16) & 1; nt = (f - 16) >> 1; }
        else if (f < 32) { W = W2a; kt = (f - 24) & 1; nt = (f - 24) >> 1; }
        else             { W = W2b; kt = (f - 32) & 1; nt = (f - 32) >> 1; }
        int col = nt * 16 + (l & 15);
        int k0  = kt * 32 + (l >> 4) * 8;
        for (int j = 0; j < 8; ++j)
            wf[f * 512 + l * 8 + j] = f16r(W[(k0 + j) * HID + col]);
    }
}

// ---------- dst histogram (int4 loads) + fused last-block exclusive scan ----------
__global__ __launch_bounds__(256) void hist_scan(const int* __restrict__ dst,
                                                 int* __restrict__ gcnt,
                                                 int* __restrict__ bbase,
                                                 int* __restrict__ bcur,
                                                 int* __restrict__ done,
                                                 int nE, int B) {
    __shared__ int lc[NBUCK];
    int t = threadIdx.x;
    for (int i = t; i < NBUCK; i += 256) lc[i] = 0;
    __syncthreads();
    int idx4 = (blockIdx.x * 256 + t) * 4;
    int stride4 = gridDim.x * 256 * 4;
    for (int e = idx4; e < nE; e += stride4) {
        if (e + 3 < nE) {
            int4 d = *(const int4*)(dst + e);
            atomicAdd(&lc[d.x >> 8], 1);
            atomicAdd(&lc[d.y >> 8], 1);
            atomicAdd(&lc[d.z >> 8], 1);
            atomicAdd(&lc[d.w >> 8], 1);
        } else {
            for (int k = e; k < nE; ++k) atomicAdd(&lc[dst[k] >> 8], 1);
        }
    }
    __syncthreads();
    for (int i = t; i < B; i += 256) {
        int c = lc[i];
        if (c) atomicAdd(&gcnt[i], c);
    }
    // last block performs the scan
    __threadfence();
    __shared__ int isLast;
    if (t == 0) {
        int old = atomicAdd(done, 1);
        isLast = (old == (int)gridDim.x - 1);
    }
    __syncthreads();
    if (isLast) {
        __shared__ int sc[NBUCK];
        sc[t]       = atomicAdd(&gcnt[t], 0);        // coherent read
        sc[t + 256] = atomicAdd(&gcnt[t + 256], 0);
        __syncthreads();
        for (int off = 1; off < NBUCK; off <<= 1) {
            int x0 = sc[t], x1 = sc[t + 256];
            int y0 = (t >= off) ? sc[t - off] : 0;
            int y1 = (t + 256 >= off) ? sc[t + 256 - off] : 0;
            __syncthreads();
            sc[t] = x0 + y0;
            sc[t + 256] = x1 + y1;
            __syncthreads();
        }
        int e0 = (t == 0) ? 0 : sc[t - 1];
        int e1 = sc[t + 255];
        bbase[t] = e0;        bcur[t] = e0;
        bbase[t + 256] = e1;  bcur[t + 256] = e1;
    }
}

// ---------- merged: blocks [0,nRounds) partition one round; rest grid-stride proj ----------
__global__ __launch_bounds__(256) void part_proj(const float* __restrict__ h,
                                                 const u16* __restrict__ wf,
                                                 u16* __restrict__ pout, int M,
                                                 const int* __restrict__ src,
                                                 const int* __restrict__ dst,
                                                 int* __restrict__ bcur,
                                                 uint* __restrict__ ebuf,
                                                 int nE, int nRounds) {
    __shared__ int rcnt[NBUCK];
    __shared__ int chunk[NBUCK];
    if ((int)blockIdx.x < nRounds) {
        int t = threadIdx.x;
        int base = (int)blockIdx.x * (EPT * 256);
        for (int i = t; i < NBUCK; i += 256) rcnt[i] = 0;
        __syncthreads();
        uint pk[EPT];
        int rb[EPT];
#pragma unroll
        for (int j = 0; j < EPT; ++j) {
            int e = base + j * 256 + t;
            rb[j] = -1;
            if (e < nE) {
                int d = dst[e];
                int b = d >> 8;
                pk[j] = (uint)src[e] | ((uint)(d & 255) << 24);
                int rk = atomicAdd(&rcnt[b], 1);
                rb[j] = (rk << 9) | b;
            }
        }
        __syncthreads();
        for (int i = t; i < NBUCK; i += 256) {
            int c = rcnt[i];
            if (c) chunk[i] = atomicAdd(&bcur[i], c);
        }
        __syncthreads();
#pragma unroll
        for (int j = 0; j < EPT; ++j) {
            if (rb[j] >= 0) {
                int b = rb[j] & 511, rk = rb[j] >> 9;
                ebuf[chunk[b] + rk] = pk[j];
            }
        }
    } else {
        int wid = threadIdx.x >> 6, lane = threadIdx.x & 63;
        int lr = lane & 15, kg = lane >> 4;
        int pb = (int)blockIdx.x - nRounds;
        int nPB = gridDim.x - nRounds;
        int tiles = (M + 63) >> 6;
        h8v bfr[16];
#pragma unroll
        for (int f = 0; f < 16; ++f)
            bfr[f] = *reinterpret_cast<const h8v*>(wf + f * 512 + lane * 8);
        f4v zero = {0.f, 0.f, 0.f, 0.f};
        for (int tile = pb; tile < tiles; tile += nPB) {
            int node0 = tile * 64 + wid * 16;
            f4v acc[4] = {zero, zero, zero, zero};
            int nodeA = min(node0 + lr, M - 1);
            const float* hp = h + (size_t)nodeA * IN_DIM + kg * 8;
#pragma unroll
            for (int kt = 0; kt < 4; ++kt) {
                float4 x = *reinterpret_cast<const float4*>(hp + kt * 32);
                float4 y = *reinterpret_cast<const float4*>(hp + kt * 32 + 4);
                h8v afr = pack8h(x, y);
#pragma unroll
                for (int nt = 0; nt < 4; ++nt)
                    acc[nt] = __builtin_amdgcn_mfma_f32_16x16x32_f16(afr, bfr[nt * 4 + kt], acc[nt], 0, 0, 0);
            }
#pragma unroll
            for (int jj = 0; jj < 4; ++jj) {
                int node = node0 + kg * 4 + jj;
                if (node < M) {
#pragma unroll
                    for (int nt = 0; nt < 4; ++nt)
                        pout[(size_t)node * HID + nt * 16 + lr] = f16r(acc[nt][jj]);
                }
            }
        }
    }
}

// ---------- one block per bucket: LDS hist+scan -> rp, dense scatter ----------
__global__ __launch_bounds__(256) void bucket_csr(const uint* __restrict__ ebuf,
                                                  const int* __restrict__ bbase,
                                                  const int* __restrict__ bcur,
                                                  int* __restrict__ rp,
                                                  int* __restrict__ ssrc,
                                                  int M, int nE) {
    __shared__ int cnt[256], sc[256], cur[256];
    int b = blockIdx.x, t = threadIdx.x;
    int ebeg = bbase[b], eend = bcur[b];
    cnt[t] = 0;
    __syncthreads();
    for (int e = ebeg + t; e < eend; e += 256) atomicAdd(&cnt[ebuf[e] >> 24], 1);
    __syncthreads();
    sc[t] = cnt[t];
    __syncthreads();
    for (int off = 1; off < 256; off <<= 1) {
        int x = sc[t];
        int y = (t >= off) ? sc[t - off] : 0;
        __syncthreads();
        sc[t] = x + y;
        __syncthreads();
    }
    int excl = (t == 0) ? 0 : sc[t - 1];
    int node = (b << 8) + t;
    if (node < M) rp[node] = ebeg + excl;
    if (b == 0 && t == 0) rp[M] = nE;
    cur[t] = excl;
    __syncthreads();
    for (int e = ebeg + t; e < eend; e += 256) {
        uint u = ebuf[e];
        int r = atomicAdd(&cur[u >> 24], 1);
        ssrc[ebeg + r] = (int)(u & 0x00ffffffu);
    }
}

// ---------- gather: 8-lane group per node, 8 row-loads in flight, packed f16 adds ----------
__global__ __launch_bounds__(256) void gather_z(const uint* __restrict__ pin,
                                                const int* __restrict__ rp,
                                                const int* __restrict__ ssrc,
                                                const float* __restrict__ ba,
                                                uint* __restrict__ zout, int M) {
    int lane = threadIdx.x & 63;
    int g = lane >> 3, q = lane & 7;
    int w = (blockIdx.x * 256 + threadIdx.x) >> 6;
    int v = w * 8 + g;
    if (v >= M) return;
    const uint4* pin4 = (const uint4*)pin;
    int beg = rp[v], end = rp[v + 1];
    uint4 u = pin4[(size_t)v * 8 + q];
    __half2 a0 = u2h(u.x), a1 = u2h(u.y), a2 = u2h(u.z), a3 = u2h(u.w);
    int e = beg;
    for (; e + 8 <= end; e += 8) {
        int s0 = ssrc[e],     s1 = ssrc[e + 1], s2 = ssrc[e + 2], s3 = ssrc[e + 3];
        int s4 = ssrc[e + 4], s5 = ssrc[e + 5], s6 = ssrc[e + 6], s7 = ssrc[e + 7];
        uint4 uA = pin4[(size_t)s0 * 8 + q];
        uint4 uB = pin4[(size_t)s1 * 8 + q];
        uint4 uC = pin4[(size_t)s2 * 8 + q];
        uint4 uD = pin4[(size_t)s3 * 8 + q];
        uint4 uE = pin4[(size_t)s4 * 8 + q];
        uint4 uF = pin4[(size_t)s5 * 8 + q];
        uint4 uG = pin4[(size_t)s6 * 8 + q];
        uint4 uH = pin4[(size_t)s7 * 8 + q];
        a0 = __hadd2(a0, __hadd2(__hadd2(__hadd2(u2h(uA.x), u2h(uB.x)), __hadd2(u2h(uC.x), u2h(uD.x))),
                                 __hadd2(__hadd2(u2h(uE.x), u2h(uF.x)), __hadd2(u2h(uG.x), u2h(uH.x)))));
        a1 = __hadd2(a1, __hadd2(__hadd2(__hadd2(u2h(uA.y), u2h(uB.y)), __hadd2(u2h(uC.y), u2h(uD.y))),
                                 __hadd2(__hadd2(u2h(uE.y), u2h(uF.y)), __hadd2(u2h(uG.y), u2h(uH.y)))));
        a2 = __hadd2(a2, __hadd2(__hadd2(__hadd2(u2h(uA.z), u2h(uB.z)), __hadd2(u2h(uC.z), u2h(uD.z))),
                                 __hadd2(__hadd2(u2h(uE.z), u2h(uF.z)), __hadd2(u2h(uG.z), u2h(uH.z)))));
        a3 = __hadd2(a3, __hadd2(__hadd2(__hadd2(u2h(uA.w), u2h(uB.w)), __hadd2(u2h(uC.w), u2h(uD.w))),
                                 __hadd2(__hadd2(u2h(uE.w), u2h(uF.w)), __hadd2(u2h(uG.w), u2h(uH.w)))));
    }
    for (; e + 4 <= end; e += 4) {
        int s0 = ssrc[e], s1 = ssrc[e + 1], s2 = ssrc[e + 2], s3 = ssrc[e + 3];
        uint4 uA = pin4[(size_t)s0 * 8 + q];
        uint4 uB = pin4[(size_t)s1 * 8 + q];
        uint4 uC = pin4[(size_t)s2 * 8 + q];
        uint4 uD = pin4[(size_t)s3 * 8 + q];
        a0 = __hadd2(a0, __hadd2(__hadd2(u2h(uA.x), u2h(uB.x)), __hadd2(u2h(uC.x), u2h(uD.x))));
        a1 = __hadd2(a1, __hadd2(__hadd2(u2h(uA.y), u2h(uB.y)), __hadd2(u2h(uC.y), u2h(uD.y))));
        a2 = __hadd2(a2, __hadd2(__hadd2(u2h(uA.z), u2h(uB.z)), __hadd2(u2h(uC.z), u2h(uD.z))));
        a3 = __hadd2(a3, __hadd2(__hadd2(u2h(uA.w), u2h(uB.w)), __hadd2(u2h(uC.w), u2h(uD.w))));
    }
    for (; e + 2 <= end; e += 2) {
        int s0 = ssrc[e], s1 = ssrc[e + 1];
        uint4 uA = pin4[(size_t)s0 * 8 + q];
        uint4 uB = pin4[(size_t)s1 * 8 + q];
        a0 = __hadd2(a0, __hadd2(u2h(uA.x), u2h(uB.x)));
        a1 = __hadd2(a1, __hadd2(u2h(uA.y), u2h(uB.y)));
        a2 = __hadd2(a2, __hadd2(u2h(uA.z), u2h(uB.z)));
        a3 = __hadd2(a3, __hadd2(u2h(uA.w), u2h(uB.w)));
    }
    if (e < end) {
        int s0 = ssrc[e];
        uint4 uA = pin4[(size_t)s0 * 8 + q];
        a0 = __hadd2(a0, u2h(uA.x));
        a1 = __hadd2(a1, u2h(uA.y));
        a2 = __hadd2(a2, u2h(uA.z));
        a3 = __hadd2(a3, u2h(uA.w));
    }
    const float2* ba2 = (const float2*)ba;
    float2 g0 = __half22float2(a0), g1 = __half22float2(a1);
    float2 g2 = __half22float2(a2), g3 = __half22float2(a3);
    float2 b0 = ba2[q * 4 + 0], b1 = ba2[q * 4 + 1], b2 = ba2[q * 4 + 2], b3 = ba2[q * 4 + 3];
    float r0 = fmaxf(g0.x + b0.x, 0.f), r1 = fmaxf(g0.y + b0.y, 0.f);
    float r2 = fmaxf(g1.x + b1.x, 0.f), r3 = fmaxf(g1.y + b1.y, 0.f);
    float r4 = fmaxf(g2.x + b2.x, 0.f), r5 = fmaxf(g2.y + b2.y, 0.f);
    float r6 = fmaxf(g3.x + b3.x, 0.f), r7 = fmaxf(g3.y + b3.y, 0.f);
    uint4 o = make_uint4(h2pack(r0, r1), h2pack(r2, r3), h2pack(r4, r5), h2pack(r6, r7));
    ((uint4*)zout)[(size_t)v * 8 + q] = o;
}

// ---------- MLP via MFMA, grid-stride with hoisted weight frags ----------
template<bool HAS_NEXT>
__global__ __launch_bounds__(256) void mlp_mfma(const u16* __restrict__ zin,
                                                const u16* __restrict__ wfb,
                                                const float* __restrict__ bb,
                                                const u16* __restrict__ wfn,
                                                u16* __restrict__ pout,
                                                float* __restrict__ fout, int M) {
    __shared__ float tls[4][16][68];   // per-wave; stride 68 (2-way aliasing = free)
    int wid = threadIdx.x >> 6, lane = threadIdx.x & 63;
    int lr = lane & 15, kg = lane >> 4;
    int tiles = (M + 63) >> 6;
    h8v bfr[8];
#pragma unroll
    for (int f = 0; f < 8; ++f)
        bfr[f] = *reinterpret_cast<const h8v*>(wfb + f * 512 + lane * 8);
    h8v wfr[8];
    if (HAS_NEXT) {
#pragma unroll
        for (int f = 0; f < 8; ++f)
            wfr[f] = *reinterpret_cast<const h8v*>(wfn + f * 512 + lane * 8);
    }
    float vb[4];
#pragma unroll
    for (int nt = 0; nt < 4; ++nt) vb[nt] = bb[nt * 16 + lr];
    f4v zero = {0.f, 0.f, 0.f, 0.f};
    for (int tile = blockIdx.x; tile < tiles; tile += gridDim.x) {
        int node0 = tile * 64 + wid * 16;
        f4v acc[4] = {zero, zero, zero, zero};
        int nodeA = min(node0 + lr, M - 1);
        const u16* zp = zin + (size_t)nodeA * HID + kg * 8;
#pragma unroll
        for (int kt = 0; kt < 2; ++kt) {
            h8v afr = *reinterpret_cast<const h8v*>(zp + kt * 32);
#pragma unroll
            for (int nt = 0; nt < 4; ++nt)
                acc[nt] = __builtin_amdgcn_mfma_f32_16x16x32_f16(afr, bfr[nt * 2 + kt], acc[nt], 0, 0, 0);
        }
        float h1[4][4];
#pragma unroll
        for (int nt = 0; nt < 4; ++nt) {
#pragma unroll
            for (int jj = 0; jj < 4; ++jj) {
                float v = acc[nt][jj] + vb[nt];
                h1[nt][jj] = (v > 0.f) ? v : v * NEG;
            }
        }
        if constexpr (!HAS_NEXT) {
#pragma unroll
            for (int jj = 0; jj < 4; ++jj) {
                int node = node0 + kg * 4 + jj;
                if (node < M) {
#pragma unroll
                    for (int nt = 0; nt < 4; ++nt)
                        fout[(size_t)node * HID + nt * 16 + lr] = h1[nt][jj];
                }
            }
        } else {
#pragma unroll
            for (int nt = 0; nt < 4; ++nt)
#pragma unroll
                for (int jj = 0; jj < 4; ++jj)
                    tls[wid][kg * 4 + jj][nt * 16 + lr] = h1[nt][jj];
            f4v acc2[4] = {zero, zero, zero, zero};
#pragma unroll
            for (int kt = 0; kt < 2; ++kt) {
                float4 x = *reinterpret_cast<const float4*>(&tls[wid][lr][kt * 32 + kg * 8]);
                float4 y = *reinterpret_cast<const float4*>(&tls[wid][lr][kt * 32 + kg * 8 + 4]);
                h8v afr = pack8h(x, y);
#pragma unroll
                for (int nt = 0; nt < 4; ++nt)
                    acc2[nt] = __builtin_amdgcn_mfma_f32_16x16x32_f16(afr, wfr[nt * 2 + kt], acc2[nt], 0, 0, 0);
            }
#pragma unroll
            for (int jj = 0; jj < 4; ++jj) {
                int node = node0 + kg * 4 + jj;
                if (node < M) {
#pragma unroll
                    for (int nt = 0; nt < 4; ++nt)
                        pout[(size_t)node * HID + nt * 16 + lr] = f16r(acc2[nt][jj]);
                }
            }
        }
    }
}

extern "C" void kernel_launch(void* const* d_in, const int* in_sizes, int n_in,
                              void* d_out, int out_size, void* d_ws, size_t ws_size,
                              hipStream_t stream) {
    const float* h   = (const float*)d_in[0];
    const int*   ei  = (const int*)d_in[1];
    const float* W1a = (const float*)d_in[2];
    const float* b1a = (const float*)d_in[3];
    const float* W1b = (const float*)d_in[4];
    const float* b1b = (const float*)d_in[5];
    const float* W2a = (const float*)d_in[6];
    const float* b2a = (const float*)d_in[7];
    const float* W2b = (const float*)d_in[8];
    const float* b2b = (const float*)d_in[9];

    int M  = in_sizes[0] / IN_DIM;  // 100000
    int nE = in_sizes[1] / 2;       // 1600000
    const int* src = ei;
    const int* dst = ei + nE;

    int B = (M + 255) >> 8;         // 391 buckets

    // workspace layout (f16 features packed as uint: 2 channels per uint)
    uint*  p1    = (uint*)d_ws;                     // M*32 uints
    uint*  p2    = p1 + (size_t)M * 32;
    uint*  z     = p2 + (size_t)M * 32;
    int*   gcnt  = (int*)(z + (size_t)M * 32);      // 512
    int*   bbase = gcnt + NBUCK;
    int*   bcur  = bbase + NBUCK;
    int*   done  = bcur + NBUCK;                    // 1 (+pad 3)
    int*   rp    = done + 4;                        // M+1
    int*   ssrc  = rp + (M + 1);                    // nE
    uint*  ebuf  = (uint*)(ssrc + nE);              // nE
    u16*   wf    = (u16*)(ebuf + nE);               // 40*512 u16

    int gB = (M + 31) / 32;                             // 3125 (8 nodes/wave)
    int mB = 512;                                       // mlp grid-stride blocks
    int pB = 784;                                       // proj grid-stride blocks
    int nRounds = (nE + EPT * 256 - 1) / (EPT * 256);   // 782

    // 1. weight frag prep (also zeroes gcnt + done)
    prep_frags<<<1, 256, 0, stream>>>(W1a, W1b, W2a, W2b, wf, gcnt, done);
    // 2. dst histogram + fused last-block scan -> bbase, bcur
    hist_scan<<<256, 256, 0, stream>>>(dst, gcnt, bbase, bcur, done, nE, B);
    // 3. partition (blocks [0,nRounds)) || proj (grid-stride, rest)
    part_proj<<<nRounds + pB, 256, 0, stream>>>(h, wf, (u16*)p1, M,
                                                src, dst, bcur, ebuf, nE, nRounds);
    // 4. per-bucket CSR finalize
    bucket_csr<<<B, 256, 0, stream>>>(ebuf, bbase, bcur, rp, ssrc, M, nE);

    // layer 1
    gather_z<<<gB, 256, 0, stream>>>(p1, rp, ssrc, b1a, z, M);
    mlp_mfma<true><<<mB, 256, 0, stream>>>((const u16*)z, wf + 16 * 512, b1b, wf + 24 * 512,
                                           (u16*)p2, nullptr, M);
    // layer 2
    gather_z<<<gB, 256, 0, stream>>>(p2, rp, ssrc, b2a, z, M);
    mlp_mfma<false><<<mB, 256, 0, stream>>>((const u16*)z, wf + 32 * 512, b2b, nullptr,
                                            nullptr, (float*)d_out, M);
}

// Round 16
// 148.316 us; speedup vs baseline: 1.0708x; 1.0708x over previous
//
#include <hip/hip_runtime.h>
#include <hip/hip_fp16.h>

#define IN_DIM 128
#define HID 64
#define NEG 0.01f
#define NBUCK 512     // padded bucket count (real B = ceil(M/256) = 391)
#define EPT 16        // edges per thread per partition round (round = 4096 edges)

typedef unsigned int uint;
typedef unsigned short u16;
typedef __attribute__((ext_vector_type(8))) _Float16 h8v;  // 8 f16 (4 VGPR) MFMA frag
typedef __attribute__((ext_vector_type(4))) float f4v;     // MFMA acc

__device__ __forceinline__ u16 f16r(float x) {
    __half h = __float2half_rn(x);
    return *reinterpret_cast<u16*>(&h);
}
__device__ __forceinline__ uint h2pack(float a, float b) {
    __half2 h = __float22half2_rn(make_float2(a, b));
    return *reinterpret_cast<uint*>(&h);
}
__device__ __forceinline__ __half2 u2h(uint u) { return *reinterpret_cast<__half2*>(&u); }
__device__ __forceinline__ h8v pack8h(float4 x, float4 y) {
    uint4 qq = make_uint4(h2pack(x.x, x.y), h2pack(x.z, x.w),
                          h2pack(y.x, y.y), h2pack(y.z, y.w));
    return *reinterpret_cast<h8v*>(&qq);
}

// ---------- weight fragment prep (+ gcnt/done zeroing) ----------
__global__ __launch_bounds__(256) void prep_frags(const float* __restrict__ W1a,
                                                  const float* __restrict__ W1b,
                                                  const float* __restrict__ W2a,
                                                  const float* __restrict__ W2b,
                                                  u16* __restrict__ wf,
                                                  int* __restrict__ gcnt,
                                                  int* __restrict__ done) {
    int t = threadIdx.x;
    for (int i = t; i < NBUCK; i += 256) gcnt[i] = 0;
    if (t == 0) *done = 0;
    for (int task = t; task < 40 * 64; task += 256) {
        int f = task >> 6, l = task & 63;
        const float* W;
        int kt, nt;
        if (f < 16)      { W = W1a; kt = f & 3;        nt = f >> 2; }
        else if (f < 24) { W = W1b; kt = (f - 16) & 1; nt = (f - 16) >> 1; }
        else if (f < 32) { W = W2a; kt = (f - 24) & 1; nt = (f - 24) >> 1; }
        else             { W = W2b; kt = (f - 32) & 1; nt = (f - 32) >> 1; }
        int col = nt * 16 + (l & 15);
        int k0  = kt * 32 + (l >> 4) * 8;
        for (int j = 0; j < 8; ++j)
            wf[f * 512 + l * 8 + j] = f16r(W[(k0 + j) * HID + col]);
    }
}

// ---------- dst histogram (int4 loads) + fused last-block exclusive scan ----------
__global__ __launch_bounds__(256) void hist_scan(const int* __restrict__ dst,
                                                 int* __restrict__ gcnt,
                                                 int* __restrict__ bbase,
                                                 int* __restrict__ bcur,
                                                 int* __restrict__ done,
                                                 int nE, int B) {
    __shared__ int lc[NBUCK];
    int t = threadIdx.x;
    for (int i = t; i < NBUCK; i += 256) lc[i] = 0;
    __syncthreads();
    int idx4 = (blockIdx.x * 256 + t) * 4;
    int stride4 = gridDim.x * 256 * 4;
    for (int e = idx4; e < nE; e += stride4) {
        if (e + 3 < nE) {
            int4 d = *(const int4*)(dst + e);
            atomicAdd(&lc[d.x >> 8], 1);
            atomicAdd(&lc[d.y >> 8], 1);
            atomicAdd(&lc[d.z >> 8], 1);
            atomicAdd(&lc[d.w >> 8], 1);
        } else {
            for (int k = e; k < nE; ++k) atomicAdd(&lc[dst[k] >> 8], 1);
        }
    }
    __syncthreads();
    for (int i = t; i < B; i += 256) {
        int c = lc[i];
        if (c) atomicAdd(&gcnt[i], c);
    }
    // last block performs the scan
    __threadfence();
    __shared__ int isLast;
    if (t == 0) {
        int old = atomicAdd(done, 1);
        isLast = (old == (int)gridDim.x - 1);
    }
    __syncthreads();
    if (isLast) {
        __shared__ int sc[NBUCK];
        sc[t]       = atomicAdd(&gcnt[t], 0);        // coherent read
        sc[t + 256] = atomicAdd(&gcnt[t + 256], 0);
        __syncthreads();
        for (int off = 1; off < NBUCK; off <<= 1) {
            int x0 = sc[t], x1 = sc[t + 256];
            int y0 = (t >= off) ? sc[t - off] : 0;
            int y1 = (t + 256 >= off) ? sc[t + 256 - off] : 0;
            __syncthreads();
            sc[t] = x0 + y0;
            sc[t + 256] = x1 + y1;
            __syncthreads();
        }
        int e0 = (t == 0) ? 0 : sc[t - 1];
        int e1 = sc[t + 255];
        bbase[t] = e0;        bcur[t] = e0;
        bbase[t + 256] = e1;  bcur[t + 256] = e1;
    }
}

// ---------- merged: blocks [0,nRounds) partition one round; rest grid-stride proj ----------
__global__ __launch_bounds__(256) void part_proj(const float* __restrict__ h,
                                                 const u16* __restrict__ wf,
                                                 u16* __restrict__ pout, int M,
                                                 const int* __restrict__ src,
                                                 const int* __restrict__ dst,
                                                 int* __restrict__ bcur,
                                                 uint* __restrict__ ebuf,
                                                 int nE, int nRounds) {
    __shared__ int rcnt[NBUCK];
    __shared__ int chunk[NBUCK];
    if ((int)blockIdx.x < nRounds) {
        int t = threadIdx.x;
        int base = (int)blockIdx.x * (EPT * 256);
        for (int i = t; i < NBUCK; i += 256) rcnt[i] = 0;
        __syncthreads();
        uint pk[EPT];
        int rb[EPT];
#pragma unroll
        for (int j = 0; j < EPT; ++j) {
            int e = base + j * 256 + t;
            rb[j] = -1;
            if (e < nE) {
                int d = dst[e];
                int b = d >> 8;
                pk[j] = (uint)src[e] | ((uint)(d & 255) << 24);
                int rk = atomicAdd(&rcnt[b], 1);
                rb[j] = (rk << 9) | b;
            }
        }
        __syncthreads();
        for (int i = t; i < NBUCK; i += 256) {
            int c = rcnt[i];
            if (c) chunk[i] = atomicAdd(&bcur[i], c);
        }
        __syncthreads();
#pragma unroll
        for (int j = 0; j < EPT; ++j) {
            if (rb[j] >= 0) {
                int b = rb[j] & 511, rk = rb[j] >> 9;
                ebuf[chunk[b] + rk] = pk[j];
            }
        }
    } else {
        int wid = threadIdx.x >> 6, lane = threadIdx.x & 63;
        int lr = lane & 15, kg = lane >> 4;
        int pb = (int)blockIdx.x - nRounds;
        int nPB = gridDim.x - nRounds;
        int tiles = (M + 63) >> 6;
        h8v bfr[16];
#pragma unroll
        for (int f = 0; f < 16; ++f)
            bfr[f] = *reinterpret_cast<const h8v*>(wf + f * 512 + lane * 8);
        f4v zero = {0.f, 0.f, 0.f, 0.f};
        for (int tile = pb; tile < tiles; tile += nPB) {
            int node0 = tile * 64 + wid * 16;
            f4v acc[4] = {zero, zero, zero, zero};
            int nodeA = min(node0 + lr, M - 1);
            const float* hp = h + (size_t)nodeA * IN_DIM + kg * 8;
#pragma unroll
            for (int kt = 0; kt < 4; ++kt) {
                float4 x = *reinterpret_cast<const float4*>(hp + kt * 32);
                float4 y = *reinterpret_cast<const float4*>(hp + kt * 32 + 4);
                h8v afr = pack8h(x, y);
#pragma unroll
                for (int nt = 0; nt < 4; ++nt)
                    acc[nt] = __builtin_amdgcn_mfma_f32_16x16x32_f16(afr, bfr[nt * 4 + kt], acc[nt], 0, 0, 0);
            }
#pragma unroll
            for (int jj = 0; jj < 4; ++jj) {
                int node = node0 + kg * 4 + jj;
                if (node < M) {
#pragma unroll
                    for (int nt = 0; nt < 4; ++nt)
                        pout[(size_t)node * HID + nt * 16 + lr] = f16r(acc[nt][jj]);
                }
            }
        }
    }
}

// ---------- one block per bucket: LDS hist+scan -> rp, dense scatter ----------
__global__ __launch_bounds__(256) void bucket_csr(const uint* __restrict__ ebuf,
                                                  const int* __restrict__ bbase,
                                                  const int* __restrict__ bcur,
                                                  int* __restrict__ rp,
                                                  int* __restrict__ ssrc,
                                                  int M, int nE) {
    __shared__ int cnt[256], sc[256], cur[256];
    int b = blockIdx.x, t = threadIdx.x;
    int ebeg = bbase[b], eend = bcur[b];
    cnt[t] = 0;
    __syncthreads();
    for (int e = ebeg + t; e < eend; e += 256) atomicAdd(&cnt[ebuf[e] >> 24], 1);
    __syncthreads();
    sc[t] = cnt[t];
    __syncthreads();
    for (int off = 1; off < 256; off <<= 1) {
        int x = sc[t];
        int y = (t >= off) ? sc[t - off] : 0;
        __syncthreads();
        sc[t] = x + y;
        __syncthreads();
    }
    int excl = (t == 0) ? 0 : sc[t - 1];
    int node = (b << 8) + t;
    if (node < M) rp[node] = ebeg + excl;
    if (b == 0 && t == 0) rp[M] = nE;
    cur[t] = excl;
    __syncthreads();
    for (int e = ebeg + t; e < eend; e += 256) {
        uint u = ebuf[e];
        int r = atomicAdd(&cur[u >> 24], 1);
        ssrc[ebeg + r] = (int)(u & 0x00ffffffu);
    }
}

// ---------- gather: 8-lane group per node, 8 row-loads in flight, packed f16 adds ----------
__global__ __launch_bounds__(256) void gather_z(const uint* __restrict__ pin,
                                                const int* __restrict__ rp,
                                                const int* __restrict__ ssrc,
                                                const float* __restrict__ ba,
                                                uint* __restrict__ zout, int M) {
    int lane = threadIdx.x & 63;
    int g = lane >> 3, q = lane & 7;
    int w = (blockIdx.x * 256 + threadIdx.x) >> 6;
    int v = w * 8 + g;
    if (v >= M) return;
    const uint4* pin4 = (const uint4*)pin;
    int beg = rp[v], end = rp[v + 1];
    uint4 u = pin4[(size_t)v * 8 + q];
    __half2 a0 = u2h(u.x), a1 = u2h(u.y), a2 = u2h(u.z), a3 = u2h(u.w);
    int e = beg;
    for (; e + 8 <= end; e += 8) {
        int s0 = ssrc[e],     s1 = ssrc[e + 1], s2 = ssrc[e + 2], s3 = ssrc[e + 3];
        int s4 = ssrc[e + 4], s5 = ssrc[e + 5], s6 = ssrc[e + 6], s7 = ssrc[e + 7];
        uint4 uA = pin4[(size_t)s0 * 8 + q];
        uint4 uB = pin4[(size_t)s1 * 8 + q];
        uint4 uC = pin4[(size_t)s2 * 8 + q];
        uint4 uD = pin4[(size_t)s3 * 8 + q];
        uint4 uE = pin4[(size_t)s4 * 8 + q];
        uint4 uF = pin4[(size_t)s5 * 8 + q];
        uint4 uG = pin4[(size_t)s6 * 8 + q];
        uint4 uH = pin4[(size_t)s7 * 8 + q];
        a0 = __hadd2(a0, __hadd2(__hadd2(__hadd2(u2h(uA.x), u2h(uB.x)), __hadd2(u2h(uC.x), u2h(uD.x))),
                                 __hadd2(__hadd2(u2h(uE.x), u2h(uF.x)), __hadd2(u2h(uG.x), u2h(uH.x)))));
        a1 = __hadd2(a1, __hadd2(__hadd2(__hadd2(u2h(uA.y), u2h(uB.y)), __hadd2(u2h(uC.y), u2h(uD.y))),
                                 __hadd2(__hadd2(u2h(uE.y), u2h(uF.y)), __hadd2(u2h(uG.y), u2h(uH.y)))));
        a2 = __hadd2(a2, __hadd2(__hadd2(__hadd2(u2h(uA.z), u2h(uB.z)), __hadd2(u2h(uC.z), u2h(uD.z))),
                                 __hadd2(__hadd2(u2h(uE.z), u2h(uF.z)), __hadd2(u2h(uG.z), u2h(uH.z)))));
        a3 = __hadd2(a3, __hadd2(__hadd2(__hadd2(u2h(uA.w), u2h(uB.w)), __hadd2(u2h(uC.w), u2h(uD.w))),
                                 __hadd2(__hadd2(u2h(uE.w), u2h(uF.w)), __hadd2(u2h(uG.w), u2h(uH.w)))));
    }
    for (; e + 4 <= end; e += 4) {
        int s0 = ssrc[e], s1 = ssrc[e + 1], s2 = ssrc[e + 2], s3 = ssrc[e + 3];
        uint4 uA = pin4[(size_t)s0 * 8 + q];
        uint4 uB = pin4[(size_t)s1 * 8 + q];
        uint4 uC = pin4[(size_t)s2 * 8 + q];
        uint4 uD = pin4[(size_t)s3 * 8 + q];
        a0 = __hadd2(a0, __hadd2(__hadd2(u2h(uA.x), u2h(uB.x)), __hadd2(u2h(uC.x), u2h(uD.x))));
        a1 = __hadd2(a1, __hadd2(__hadd2(u2h(uA.y), u2h(uB.y)), __hadd2(u2h(uC.y), u2h(uD.y))));
        a2 = __hadd2(a2, __hadd2(__hadd2(u2h(uA.z), u2h(uB.z)), __hadd2(u2h(uC.z), u2h(uD.z))));
        a3 = __hadd2(a3, __hadd2(__hadd2(u2h(uA.w), u2h(uB.w)), __hadd2(u2h(uC.w), u2h(uD.w))));
    }
    for (; e + 2 <= end; e += 2) {
        int s0 = ssrc[e], s1 = ssrc[e + 1];
        uint4 uA = pin4[(size_t)s0 * 8 + q];
        uint4 uB = pin4[(size_t)s1 * 8 + q];
        a0 = __hadd2(a0, __hadd2(u2h(uA.x), u2h(uB.x)));
        a1 = __hadd2(a1, __hadd2(u2h(uA.y), u2h(uB.y)));
        a2 = __hadd2(a2, __hadd2(u2h(uA.z), u2h(uB.z)));
        a3 = __hadd2(a3, __hadd2(u2h(uA.w), u2h(uB.w)));
    }
    if (e < end) {
        int s0 = ssrc[e];
        uint4 uA = pin4[(size_t)s0 * 8 + q];
        a0 = __hadd2(a0, u2h(uA.x));
        a1 = __hadd2(a1, u2h(uA.y));
        a2 = __hadd2(a2, u2h(uA.z));
        a3 = __hadd2(a3, u2h(uA.w));
    }
    const float2* ba2 = (const float2*)ba;
    float2 g0 = __half22float2(a0), g1 = __half22float2(a1);
    float2 g2 = __half22float2(a2), g3 = __half22float2(a3);
    float2 b0 = ba2[q * 4 + 0], b1 = ba2[q * 4 + 1], b2 = ba2[q * 4 + 2], b3 = ba2[q * 4 + 3];
    float r0 = fmaxf(g0.x + b0.x, 0.f), r1 = fmaxf(g0.y + b0.y, 0.f);
    float r2 = fmaxf(g1.x + b1.x, 0.f), r3 = fmaxf(g1.y + b1.y, 0.f);
    float r4 = fmaxf(g2.x + b2.x, 0.f), r5 = fmaxf(g2.y + b2.y, 0.f);
    float r6 = fmaxf(g3.x + b3.x, 0.f), r7 = fmaxf(g3.y + b3.y, 0.f);
    uint4 o = make_uint4(h2pack(r0, r1), h2pack(r2, r3), h2pack(r4, r5), h2pack(r6, r7));
    ((uint4*)zout)[(size_t)v * 8 + q] = o;
}

// ---------- MLP via MFMA, grid-stride with hoisted weight frags ----------
template<bool HAS_NEXT>
__global__ __launch_bounds__(256) void mlp_mfma(const u16* __restrict__ zin,
                                                const u16* __restrict__ wfb,
                                                const float* __restrict__ bb,
                                                const u16* __restrict__ wfn,
                                                u16* __restrict__ pout,
                                                float* __restrict__ fout, int M) {
    __shared__ float tls[4][16][68];   // per-wave; stride 68 (2-way aliasing = free)
    int wid = threadIdx.x >> 6, lane = threadIdx.x & 63;
    int lr = lane & 15, kg = lane >> 4;
    int tiles = (M + 63) >> 6;
    h8v bfr[8];
#pragma unroll
    for (int f = 0; f < 8; ++f)
        bfr[f] = *reinterpret_cast<const h8v*>(wfb + f * 512 + lane * 8);
    h8v wfr[8];
    if (HAS_NEXT) {
#pragma unroll
        for (int f = 0; f < 8; ++f)
            wfr[f] = *reinterpret_cast<const h8v*>(wfn + f * 512 + lane * 8);
    }
    float vb[4];
#pragma unroll
    for (int nt = 0; nt < 4; ++nt) vb[nt] = bb[nt * 16 + lr];
    f4v zero = {0.f, 0.f, 0.f, 0.f};
    for (int tile = blockIdx.x; tile < tiles; tile += gridDim.x) {
        int node0 = tile * 64 + wid * 16;
        f4v acc[4] = {zero, zero, zero, zero};
        int nodeA = min(node0 + lr, M - 1);
        const u16* zp = zin + (size_t)nodeA * HID + kg * 8;
#pragma unroll
        for (int kt = 0; kt < 2; ++kt) {
            h8v afr = *reinterpret_cast<const h8v*>(zp + kt * 32);
#pragma unroll
            for (int nt = 0; nt < 4; ++nt)
                acc[nt] = __builtin_amdgcn_mfma_f32_16x16x32_f16(afr, bfr[nt * 2 + kt], acc[nt], 0, 0, 0);
        }
        float h1[4][4];
#pragma unroll
        for (int nt = 0; nt < 4; ++nt) {
#pragma unroll
            for (int jj = 0; jj < 4; ++jj) {
                float v = acc[nt][jj] + vb[nt];
                h1[nt][jj] = (v > 0.f) ? v : v * NEG;
            }
        }
        if constexpr (!HAS_NEXT) {
#pragma unroll
            for (int jj = 0; jj < 4; ++jj) {
                int node = node0 + kg * 4 + jj;
                if (node < M) {
#pragma unroll
                    for (int nt = 0; nt < 4; ++nt)
                        fout[(size_t)node * HID + nt * 16 + lr] = h1[nt][jj];
                }
            }
        } else {
#pragma unroll
            for (int nt = 0; nt < 4; ++nt)
#pragma unroll
                for (int jj = 0; jj < 4; ++jj)
                    tls[wid][kg * 4 + jj][nt * 16 + lr] = h1[nt][jj];
            f4v acc2[4] = {zero, zero, zero, zero};
#pragma unroll
            for (int kt = 0; kt < 2; ++kt) {
                float4 x = *reinterpret_cast<const float4*>(&tls[wid][lr][kt * 32 + kg * 8]);
                float4 y = *reinterpret_cast<const float4*>(&tls[wid][lr][kt * 32 + kg * 8 + 4]);
                h8v afr = pack8h(x, y);
#pragma unroll
                for (int nt = 0; nt < 4; ++nt)
                    acc2[nt] = __builtin_amdgcn_mfma_f32_16x16x32_f16(afr, wfr[nt * 2 + kt], acc2[nt], 0, 0, 0);
            }
#pragma unroll
            for (int jj = 0; jj < 4; ++jj) {
                int node = node0 + kg * 4 + jj;
                if (node < M) {
#pragma unroll
                    for (int nt = 0; nt < 4; ++nt)
                        pout[(size_t)node * HID + nt * 16 + lr] = f16r(acc2[nt][jj]);
                }
            }
        }
    }
}

extern "C" void kernel_launch(void* const* d_in, const int* in_sizes, int n_in,
                              void* d_out, int out_size, void* d_ws, size_t ws_size,
                              hipStream_t stream) {
    const float* h   = (const float*)d_in[0];
    const int*   ei  = (const int*)d_in[1];
    const float* W1a = (const float*)d_in[2];
    const float* b1a = (const float*)d_in[3];
    const float* W1b = (const float*)d_in[4];
    const float* b1b = (const float*)d_in[5];
    const float* W2a = (const float*)d_in[6];
    const float* b2a = (const float*)d_in[7];
    const float* W2b = (const float*)d_in[8];
    const float* b2b = (const float*)d_in[9];

    int M  = in_sizes[0] / IN_DIM;  // 100000
    int nE = in_sizes[1] / 2;       // 1600000
    const int* src = ei;
    const int* dst = ei + nE;

    int B = (M + 255) >> 8;         // 391 buckets

    // workspace layout (f16 features packed as uint: 2 channels per uint)
    uint*  p1    = (uint*)d_ws;                     // M*32 uints
    uint*  p2    = p1 + (size_t)M * 32;
    uint*  z     = p2 + (size_t)M * 32;
    int*   gcnt  = (int*)(z + (size_t)M * 32);      // 512
    int*   bbase = gcnt + NBUCK;
    int*   bcur  = bbase + NBUCK;
    int*   done  = bcur + NBUCK;                    // 1 (+pad 3)
    int*   rp    = done + 4;                        // M+1
    int*   ssrc  = rp + (M + 1);                    // nE
    uint*  ebuf  = (uint*)(ssrc + nE);              // nE
    u16*   wf    = (u16*)(ebuf + nE);               // 40*512 u16

    int gB = (M + 31) / 32;                             // 3125 (8 nodes/wave)
    int mB = 512;                                       // mlp grid-stride blocks
    int pB = 784;                                       // proj grid-stride blocks
    int nRounds = (nE + EPT * 256 - 1) / (EPT * 256);   // 391

    // 1. weight frag prep (also zeroes gcnt + done)
    prep_frags<<<1, 256, 0, stream>>>(W1a, W1b, W2a, W2b, wf, gcnt, done);
    // 2. dst histogram + fused last-block scan -> bbase, bcur
    hist_scan<<<256, 256, 0, stream>>>(dst, gcnt, bbase, bcur, done, nE, B);
    // 3. partition (blocks [0,nRounds)) || proj (grid-stride, rest)
    part_proj<<<nRounds + pB, 256, 0, stream>>>(h, wf, (u16*)p1, M,
                                                src, dst, bcur, ebuf, nE, nRounds);
    // 4. per-bucket CSR finalize
    bucket_csr<<<B, 256, 0, stream>>>(ebuf, bbase, bcur, rp, ssrc, M, nE);

    // layer 1
    gather_z<<<gB, 256, 0, stream>>>(p1, rp, ssrc, b1a, z, M);
    mlp_mfma<true><<<mB, 256, 0, stream>>>((const u16*)z, wf + 16 * 512, b1b, wf + 24 * 512,
                                           (u16*)p2, nullptr, M);
    // layer 2
    gather_z<<<gB, 256, 0, stream>>>(p2, rp, ssrc, b2a, z, M);
    mlp_mfma<false><<<mB, 256, 0, stream>>>((const u16*)z, wf + 32 * 512, b2b, nullptr,
                                            nullptr, (float*)d_out, M);
}

// Round 17
// 138.760 us; speedup vs baseline: 1.1446x; 1.0689x over previous
//
#include <hip/hip_runtime.h>
#include <hip/hip_fp16.h>

#define IN_DIM 128
#define HID 64
#define NEG 0.01f
#define NBUCK 512     // padded bucket count (real B = ceil(M/256) = 391)
#define EPT 32        // edges per thread per partition round (round = 8192 edges -> 64B chunks)

typedef unsigned int uint;
typedef unsigned short u16;
typedef __attribute__((ext_vector_type(8))) _Float16 h8v;  // 8 f16 (4 VGPR) MFMA frag
typedef __attribute__((ext_vector_type(4))) float f4v;     // MFMA acc

__device__ __forceinline__ u16 f16r(float x) {
    __half h = __float2half_rn(x);
    return *reinterpret_cast<u16*>(&h);
}
__device__ __forceinline__ uint h2pack(float a, float b) {
    __half2 h = __float22half2_rn(make_float2(a, b));
    return *reinterpret_cast<uint*>(&h);
}
__device__ __forceinline__ __half2 u2h(uint u) { return *reinterpret_cast<__half2*>(&u); }
__device__ __forceinline__ h8v pack8h(float4 x, float4 y) {
    uint4 qq = make_uint4(h2pack(x.x, x.y), h2pack(x.z, x.w),
                          h2pack(y.x, y.y), h2pack(y.z, y.w));
    return *reinterpret_cast<h8v*>(&qq);
}

// ---------- weight fragment prep (+ gcnt zeroing) ----------
__global__ __launch_bounds__(256) void prep_frags(const float* __restrict__ W1a,
                                                  const float* __restrict__ W1b,
                                                  const float* __restrict__ W2a,
                                                  const float* __restrict__ W2b,
                                                  u16* __restrict__ wf,
                                                  int* __restrict__ gcnt) {
    int t = threadIdx.x;
    for (int i = t; i < NBUCK; i += 256) gcnt[i] = 0;
    for (int task = t; task < 40 * 64; task += 256) {
        int f = task >> 6, l = task & 63;
        const float* W;
        int kt, nt;
        if (f < 16)      { W = W1a; kt = f & 3;        nt = f >> 2; }
        else if (f < 24) { W = W1b; kt = (f - 16) & 1; nt = (f - 16) >> 1; }
        else if (f < 32) { W = W2a; kt = (f - 24) & 1; nt = (f - 24) >> 1; }
        else             { W = W2b; kt = (f - 32) & 1; nt = (f - 32) >> 1; }
        int col = nt * 16 + (l & 15);
        int k0  = kt * 32 + (l >> 4) * 8;
        for (int j = 0; j < 8; ++j)
            wf[f * 512 + l * 8 + j] = f16r(W[(k0 + j) * HID + col]);
    }
}

// ---------- dst histogram ----------
__global__ __launch_bounds__(256) void hist(const int* __restrict__ dst,
                                            int* __restrict__ gcnt, int nE, int B) {
    __shared__ int lc[NBUCK];
    for (int i = threadIdx.x; i < NBUCK; i += 256) lc[i] = 0;
    __syncthreads();
    int idx = blockIdx.x * 256 + threadIdx.x;
    int stride = gridDim.x * 256;
    for (int e = idx; e < nE; e += stride) atomicAdd(&lc[dst[e] >> 8], 1);
    __syncthreads();
    for (int i = threadIdx.x; i < B; i += 256) {
        int c = lc[i];
        if (c) atomicAdd(&gcnt[i], c);
    }
}

// ---------- exclusive scan of gcnt[512] -> bbase, bcur ----------
__global__ __launch_bounds__(256) void coarse_scan(const int* __restrict__ gcnt,
                                                   int* __restrict__ bbase,
                                                   int* __restrict__ bcur) {
    __shared__ int sc[NBUCK];
    int t = threadIdx.x;
    sc[t] = gcnt[t];
    sc[t + 256] = gcnt[t + 256];
    __syncthreads();
    for (int off = 1; off < NBUCK; off <<= 1) {
        int x0 = sc[t], x1 = sc[t + 256];
        int y0 = (t >= off) ? sc[t - off] : 0;
        int y1 = (t + 256 >= off) ? sc[t + 256 - off] : 0;
        __syncthreads();
        sc[t] = x0 + y0;
        sc[t + 256] = x1 + y1;
        __syncthreads();
    }
    int e0 = (t == 0) ? 0 : sc[t - 1];
    int e1 = sc[t + 255];
    bbase[t] = e0;        bcur[t] = e0;
    bbase[t + 256] = e1;  bcur[t + 256] = e1;
}

// ---------- merged: blocks [0,nRounds) partition one round; rest grid-stride proj ----------
__global__ __launch_bounds__(256) void part_proj(const float* __restrict__ h,
                                                 const u16* __restrict__ wf,
                                                 u16* __restrict__ pout, int M,
                                                 const int* __restrict__ src,
                                                 const int* __restrict__ dst,
                                                 int* __restrict__ bcur,
                                                 uint* __restrict__ ebuf,
                                                 int nE, int nRounds) {
    __shared__ int rcnt[NBUCK];
    __shared__ int chunk[NBUCK];
    if ((int)blockIdx.x < nRounds) {
        int t = threadIdx.x;
        int base = (int)blockIdx.x * (EPT * 256);
        for (int i = t; i < NBUCK; i += 256) rcnt[i] = 0;
        __syncthreads();
        uint pk[EPT];
        int rb[EPT];
#pragma unroll
        for (int j = 0; j < EPT; ++j) {
            int e = base + j * 256 + t;
            rb[j] = -1;
            if (e < nE) {
                int d = dst[e];
                int b = d >> 8;
                pk[j] = (uint)src[e] | ((uint)(d & 255) << 24);
                int rk = atomicAdd(&rcnt[b], 1);
                rb[j] = (rk << 9) | b;
            }
        }
        __syncthreads();
        for (int i = t; i < NBUCK; i += 256) {
            int c = rcnt[i];
            if (c) chunk[i] = atomicAdd(&bcur[i], c);
        }
        __syncthreads();
#pragma unroll
        for (int j = 0; j < EPT; ++j) {
            if (rb[j] >= 0) {
                int b = rb[j] & 511, rk = rb[j] >> 9;
                ebuf[chunk[b] + rk] = pk[j];
            }
        }
    } else {
        int wid = threadIdx.x >> 6, lane = threadIdx.x & 63;
        int lr = lane & 15, kg = lane >> 4;
        int pb = (int)blockIdx.x - nRounds;
        int nPB = gridDim.x - nRounds;
        int tiles = (M + 63) >> 6;
        h8v bfr[16];
#pragma unroll
        for (int f = 0; f < 16; ++f)
            bfr[f] = *reinterpret_cast<const h8v*>(wf + f * 512 + lane * 8);
        f4v zero = {0.f, 0.f, 0.f, 0.f};
        for (int tile = pb; tile < tiles; tile += nPB) {
            int node0 = tile * 64 + wid * 16;
            f4v acc[4] = {zero, zero, zero, zero};
            int nodeA = min(node0 + lr, M - 1);
            const float* hp = h + (size_t)nodeA * IN_DIM + kg * 8;
#pragma unroll
            for (int kt = 0; kt < 4; ++kt) {
                float4 x = *reinterpret_cast<const float4*>(hp + kt * 32);
                float4 y = *reinterpret_cast<const float4*>(hp + kt * 32 + 4);
                h8v afr = pack8h(x, y);
#pragma unroll
                for (int nt = 0; nt < 4; ++nt)
                    acc[nt] = __builtin_amdgcn_mfma_f32_16x16x32_f16(afr, bfr[nt * 4 + kt], acc[nt], 0, 0, 0);
            }
#pragma unroll
            for (int jj = 0; jj < 4; ++jj) {
                int node = node0 + kg * 4 + jj;
                if (node < M) {
#pragma unroll
                    for (int nt = 0; nt < 4; ++nt)
                        pout[(size_t)node * HID + nt * 16 + lr] = f16r(acc[nt][jj]);
                }
            }
        }
    }
}

// ---------- one block per bucket: LDS hist+scan -> rp, dense scatter ----------
__global__ __launch_bounds__(256) void bucket_csr(const uint* __restrict__ ebuf,
                                                  const int* __restrict__ bbase,
                                                  const int* __restrict__ bcur,
                                                  int* __restrict__ rp,
                                                  int* __restrict__ ssrc,
                                                  int M, int nE) {
    __shared__ int cnt[256], sc[256], cur[256];
    int b = blockIdx.x, t = threadIdx.x;
    int ebeg = bbase[b], eend = bcur[b];
    cnt[t] = 0;
    __syncthreads();
    for (int e = ebeg + t; e < eend; e += 256) atomicAdd(&cnt[ebuf[e] >> 24], 1);
    __syncthreads();
    sc[t] = cnt[t];
    __syncthreads();
    for (int off = 1; off < 256; off <<= 1) {
        int x = sc[t];
        int y = (t >= off) ? sc[t - off] : 0;
        __syncthreads();
        sc[t] = x + y;
        __syncthreads();
    }
    int excl = (t == 0) ? 0 : sc[t - 1];
    int node = (b << 8) + t;
    if (node < M) rp[node] = ebeg + excl;
    if (b == 0 && t == 0) rp[M] = nE;
    cur[t] = excl;
    __syncthreads();
    for (int e = ebeg + t; e < eend; e += 256) {
        uint u = ebuf[e];
        int r = atomicAdd(&cur[u >> 24], 1);
        ssrc[ebeg + r] = (int)(u & 0x00ffffffu);
    }
}

// ---------- gather: 8-lane group per node, 8 row-loads in flight, packed f16 adds ----------
__global__ __launch_bounds__(256) void gather_z(const uint* __restrict__ pin,
                                                const int* __restrict__ rp,
                                                const int* __restrict__ ssrc,
                                                const float* __restrict__ ba,
                                                uint* __restrict__ zout, int M) {
    int lane = threadIdx.x & 63;
    int g = lane >> 3, q = lane & 7;
    int w = (blockIdx.x * 256 + threadIdx.x) >> 6;
    int v = w * 8 + g;
    if (v >= M) return;
    const uint4* pin4 = (const uint4*)pin;
    int beg = rp[v], end = rp[v + 1];
    uint4 u = pin4[(size_t)v * 8 + q];
    __half2 a0 = u2h(u.x), a1 = u2h(u.y), a2 = u2h(u.z), a3 = u2h(u.w);
    int e = beg;
    for (; e + 8 <= end; e += 8) {
        int s0 = ssrc[e],     s1 = ssrc[e + 1], s2 = ssrc[e + 2], s3 = ssrc[e + 3];
        int s4 = ssrc[e + 4], s5 = ssrc[e + 5], s6 = ssrc[e + 6], s7 = ssrc[e + 7];
        uint4 uA = pin4[(size_t)s0 * 8 + q];
        uint4 uB = pin4[(size_t)s1 * 8 + q];
        uint4 uC = pin4[(size_t)s2 * 8 + q];
        uint4 uD = pin4[(size_t)s3 * 8 + q];
        uint4 uE = pin4[(size_t)s4 * 8 + q];
        uint4 uF = pin4[(size_t)s5 * 8 + q];
        uint4 uG = pin4[(size_t)s6 * 8 + q];
        uint4 uH = pin4[(size_t)s7 * 8 + q];
        a0 = __hadd2(a0, __hadd2(__hadd2(__hadd2(u2h(uA.x), u2h(uB.x)), __hadd2(u2h(uC.x), u2h(uD.x))),
                                 __hadd2(__hadd2(u2h(uE.x), u2h(uF.x)), __hadd2(u2h(uG.x), u2h(uH.x)))));
        a1 = __hadd2(a1, __hadd2(__hadd2(__hadd2(u2h(uA.y), u2h(uB.y)), __hadd2(u2h(uC.y), u2h(uD.y))),
                                 __hadd2(__hadd2(u2h(uE.y), u2h(uF.y)), __hadd2(u2h(uG.y), u2h(uH.y)))));
        a2 = __hadd2(a2, __hadd2(__hadd2(__hadd2(u2h(uA.z), u2h(uB.z)), __hadd2(u2h(uC.z), u2h(uD.z))),
                                 __hadd2(__hadd2(u2h(uE.z), u2h(uF.z)), __hadd2(u2h(uG.z), u2h(uH.z)))));
        a3 = __hadd2(a3, __hadd2(__hadd2(__hadd2(u2h(uA.w), u2h(uB.w)), __hadd2(u2h(uC.w), u2h(uD.w))),
                                 __hadd2(__hadd2(u2h(uE.w), u2h(uF.w)), __hadd2(u2h(uG.w), u2h(uH.w)))));
    }
    for (; e + 4 <= end; e += 4) {
        int s0 = ssrc[e], s1 = ssrc[e + 1], s2 = ssrc[e + 2], s3 = ssrc[e + 3];
        uint4 uA = pin4[(size_t)s0 * 8 + q];
        uint4 uB = pin4[(size_t)s1 * 8 + q];
        uint4 uC = pin4[(size_t)s2 * 8 + q];
        uint4 uD = pin4[(size_t)s3 * 8 + q];
        a0 = __hadd2(a0, __hadd2(__hadd2(u2h(uA.x), u2h(uB.x)), __hadd2(u2h(uC.x), u2h(uD.x))));
        a1 = __hadd2(a1, __hadd2(__hadd2(u2h(uA.y), u2h(uB.y)), __hadd2(u2h(uC.y), u2h(uD.y))));
        a2 = __hadd2(a2, __hadd2(__hadd2(u2h(uA.z), u2h(uB.z)), __hadd2(u2h(uC.z), u2h(uD.z))));
        a3 = __hadd2(a3, __hadd2(__hadd2(u2h(uA.w), u2h(uB.w)), __hadd2(u2h(uC.w), u2h(uD.w))));
    }
    for (; e + 2 <= end; e += 2) {
        int s0 = ssrc[e], s1 = ssrc[e + 1];
        uint4 uA = pin4[(size_t)s0 * 8 + q];
        uint4 uB = pin4[(size_t)s1 * 8 + q];
        a0 = __hadd2(a0, __hadd2(u2h(uA.x), u2h(uB.x)));
        a1 = __hadd2(a1, __hadd2(u2h(uA.y), u2h(uB.y)));
        a2 = __hadd2(a2, __hadd2(u2h(uA.z), u2h(uB.z)));
        a3 = __hadd2(a3, __hadd2(u2h(uA.w), u2h(uB.w)));
    }
    if (e < end) {
        int s0 = ssrc[e];
        uint4 uA = pin4[(size_t)s0 * 8 + q];
        a0 = __hadd2(a0, u2h(uA.x));
        a1 = __hadd2(a1, u2h(uA.y));
        a2 = __hadd2(a2, u2h(uA.z));
        a3 = __hadd2(a3, u2h(uA.w));
    }
    const float2* ba2 = (const float2*)ba;
    float2 g0 = __half22float2(a0), g1 = __half22float2(a1);
    float2 g2 = __half22float2(a2), g3 = __half22float2(a3);
    float2 b0 = ba2[q * 4 + 0], b1 = ba2[q * 4 + 1], b2 = ba2[q * 4 + 2], b3 = ba2[q * 4 + 3];
    float r0 = fmaxf(g0.x + b0.x, 0.f), r1 = fmaxf(g0.y + b0.y, 0.f);
    float r2 = fmaxf(g1.x + b1.x, 0.f), r3 = fmaxf(g1.y + b1.y, 0.f);
    float r4 = fmaxf(g2.x + b2.x, 0.f), r5 = fmaxf(g2.y + b2.y, 0.f);
    float r6 = fmaxf(g3.x + b3.x, 0.f), r7 = fmaxf(g3.y + b3.y, 0.f);
    uint4 o = make_uint4(h2pack(r0, r1), h2pack(r2, r3), h2pack(r4, r5), h2pack(r6, r7));
    ((uint4*)zout)[(size_t)v * 8 + q] = o;
}

// ---------- MLP via MFMA, grid-stride with hoisted weight frags ----------
template<bool HAS_NEXT>
__global__ __launch_bounds__(256) void mlp_mfma(const u16* __restrict__ zin,
                                                const u16* __restrict__ wfb,
                                                const float* __restrict__ bb,
                                                const u16* __restrict__ wfn,
                                                u16* __restrict__ pout,
                                                float* __restrict__ fout, int M) {
    __shared__ float tls[4][16][68];   // per-wave; stride 68 (2-way aliasing = free)
    int wid = threadIdx.x >> 6, lane = threadIdx.x & 63;
    int lr = lane & 15, kg = lane >> 4;
    int tiles = (M + 63) >> 6;
    h8v bfr[8];
#pragma unroll
    for (int f = 0; f < 8; ++f)
        bfr[f] = *reinterpret_cast<const h8v*>(wfb + f * 512 + lane * 8);
    h8v wfr[8];
    if (HAS_NEXT) {
#pragma unroll
        for (int f = 0; f < 8; ++f)
            wfr[f] = *reinterpret_cast<const h8v*>(wfn + f * 512 + lane * 8);
    }
    float vb[4];
#pragma unroll
    for (int nt = 0; nt < 4; ++nt) vb[nt] = bb[nt * 16 + lr];
    f4v zero = {0.f, 0.f, 0.f, 0.f};
    for (int tile = blockIdx.x; tile < tiles; tile += gridDim.x) {
        int node0 = tile * 64 + wid * 16;
        f4v acc[4] = {zero, zero, zero, zero};
        int nodeA = min(node0 + lr, M - 1);
        const u16* zp = zin + (size_t)nodeA * HID + kg * 8;
#pragma unroll
        for (int kt = 0; kt < 2; ++kt) {
            h8v afr = *reinterpret_cast<const h8v*>(zp + kt * 32);
#pragma unroll
            for (int nt = 0; nt < 4; ++nt)
                acc[nt] = __builtin_amdgcn_mfma_f32_16x16x32_f16(afr, bfr[nt * 2 + kt], acc[nt], 0, 0, 0);
        }
        float h1[4][4];
#pragma unroll
        for (int nt = 0; nt < 4; ++nt) {
#pragma unroll
            for (int jj = 0; jj < 4; ++jj) {
                float v = acc[nt][jj] + vb[nt];
                h1[nt][jj] = (v > 0.f) ? v : v * NEG;
            }
        }
        if constexpr (!HAS_NEXT) {
#pragma unroll
            for (int jj = 0; jj < 4; ++jj) {
                int node = node0 + kg * 4 + jj;
                if (node < M) {
#pragma unroll
                    for (int nt = 0; nt < 4; ++nt)
                        fout[(size_t)node * HID + nt * 16 + lr] = h1[nt][jj];
                }
            }
        } else {
#pragma unroll
            for (int nt = 0; nt < 4; ++nt)
#pragma unroll
                for (int jj = 0; jj < 4; ++jj)
                    tls[wid][kg * 4 + jj][nt * 16 + lr] = h1[nt][jj];
            f4v acc2[4] = {zero, zero, zero, zero};
#pragma unroll
            for (int kt = 0; kt < 2; ++kt) {
                float4 x = *reinterpret_cast<const float4*>(&tls[wid][lr][kt * 32 + kg * 8]);
                float4 y = *reinterpret_cast<const float4*>(&tls[wid][lr][kt * 32 + kg * 8 + 4]);
                h8v afr = pack8h(x, y);
#pragma unroll
                for (int nt = 0; nt < 4; ++nt)
                    acc2[nt] = __builtin_amdgcn_mfma_f32_16x16x32_f16(afr, wfr[nt * 2 + kt], acc2[nt], 0, 0, 0);
            }
#pragma unroll
            for (int jj = 0; jj < 4; ++jj) {
                int node = node0 + kg * 4 + jj;
                if (node < M) {
#pragma unroll
                    for (int nt = 0; nt < 4; ++nt)
                        pout[(size_t)node * HID + nt * 16 + lr] = f16r(acc2[nt][jj]);
                }
            }
        }
    }
}

extern "C" void kernel_launch(void* const* d_in, const int* in_sizes, int n_in,
                              void* d_out, int out_size, void* d_ws, size_t ws_size,
                              hipStream_t stream) {
    const float* h   = (const float*)d_in[0];
    const int*   ei  = (const int*)d_in[1];
    const float* W1a = (const float*)d_in[2];
    const float* b1a = (const float*)d_in[3];
    const float* W1b = (const float*)d_in[4];
    const float* b1b = (const float*)d_in[5];
    const float* W2a = (const float*)d_in[6];
    const float* b2a = (const float*)d_in[7];
    const float* W2b = (const float*)d_in[8];
    const float* b2b = (const float*)d_in[9];

    int M  = in_sizes[0] / IN_DIM;  // 100000
    int nE = in_sizes[1] / 2;       // 1600000
    const int* src = ei;
    const int* dst = ei + nE;

    int B = (M + 255) >> 8;         // 391 buckets

    // workspace layout (f16 features packed as uint: 2 channels per uint)
    uint*  p1    = (uint*)d_ws;                     // M*32 uints
    uint*  p2    = p1 + (size_t)M * 32;
    uint*  z     = p2 + (size_t)M * 32;
    int*   gcnt  = (int*)(z + (size_t)M * 32);      // 512
    int*   bbase = gcnt + NBUCK;
    int*   bcur  = bbase + NBUCK;
    int*   rp    = bcur + NBUCK;                    // M+1
    int*   ssrc  = rp + (M + 1);                    // nE
    uint*  ebuf  = (uint*)(ssrc + nE);              // nE
    u16*   wf    = (u16*)(ebuf + nE);               // 40*512 u16

    int gB = (M + 31) / 32;                             // 3125 (8 nodes/wave)
    int mB = 512;                                       // mlp grid-stride blocks
    int pB = 784;                                       // proj grid-stride blocks
    int nRounds = (nE + EPT * 256 - 1) / (EPT * 256);   // 196

    // 1. weight frag prep (also zeroes gcnt)
    prep_frags<<<1, 256, 0, stream>>>(W1a, W1b, W2a, W2b, wf, gcnt);
    // 2. dst histogram
    hist<<<256, 256, 0, stream>>>(dst, gcnt, nE, B);
    // 3. bucket base scan
    coarse_scan<<<1, 256, 0, stream>>>(gcnt, bbase, bcur);
    // 4. partition (blocks [0,nRounds)) || proj (grid-stride, rest)
    part_proj<<<nRounds + pB, 256, 0, stream>>>(h, wf, (u16*)p1, M,
                                                src, dst, bcur, ebuf, nE, nRounds);
    // 5. per-bucket CSR finalize
    bucket_csr<<<B, 256, 0, stream>>>(ebuf, bbase, bcur, rp, ssrc, M, nE);

    // layer 1
    gather_z<<<gB, 256, 0, stream>>>(p1, rp, ssrc, b1a, z, M);
    mlp_mfma<true><<<mB, 256, 0, stream>>>((const u16*)z, wf + 16 * 512, b1b, wf + 24 * 512,
                                           (u16*)p2, nullptr, M);
    // layer 2
    gather_z<<<gB, 256, 0, stream>>>(p2, rp, ssrc, b2a, z, M);
    mlp_mfma<false><<<mB, 256, 0, stream>>>((const u16*)z, wf + 32 * 512, b2b, nullptr,
                                            nullptr, (float*)d_out, M);
}